// Round 1
// baseline (512.955 us; speedup 1.0000x reference)
//
#include <hip/hip_runtime.h>

#define NN 50000
#define NE 800000
#define FD 128
#define NC 16
#define SLOPE 0.05f

// ---------------- GEMM: Y[NN,128] = X[NN,128] @ W[128,128] ----------------
// W staged in LDS (64KB). Each wave computes 4 rows x 128 cols; lane l owns
// cols {2l, 2l+1}. 16 rows per block-iteration (4 waves). 50000 % 16 == 0.
__global__ __launch_bounds__(256) void k_gemm128(const float* __restrict__ X,
                                                 const float* __restrict__ W,
                                                 float* __restrict__ Y) {
    __shared__ float Wl[FD * FD];
    for (int i = threadIdx.x * 4; i < FD * FD; i += 256 * 4)
        *(float4*)&Wl[i] = *(const float4*)&W[i];
    __syncthreads();
    const int wave = threadIdx.x >> 6;
    const int lane = threadIdx.x & 63;
    for (int base = blockIdx.x * 16; base < NN; base += gridDim.x * 16) {
        const int r0 = base + wave * 4;
        const float* __restrict__ x0 = X + (size_t)r0 * FD;
        float2 acc0 = make_float2(0.f, 0.f), acc1 = acc0, acc2 = acc0, acc3 = acc0;
#pragma unroll 4
        for (int k = 0; k < FD; k += 4) {
            float4 a0 = *(const float4*)&x0[k];
            float4 a1 = *(const float4*)&x0[FD + k];
            float4 a2 = *(const float4*)&x0[2 * FD + k];
            float4 a3 = *(const float4*)&x0[3 * FD + k];
#pragma unroll
            for (int kk = 0; kk < 4; ++kk) {
                float2 wv = *(const float2*)&Wl[(k + kk) * FD + lane * 2];
                float b0 = (&a0.x)[kk], b1 = (&a1.x)[kk], b2 = (&a2.x)[kk], b3 = (&a3.x)[kk];
                acc0.x = fmaf(b0, wv.x, acc0.x); acc0.y = fmaf(b0, wv.y, acc0.y);
                acc1.x = fmaf(b1, wv.x, acc1.x); acc1.y = fmaf(b1, wv.y, acc1.y);
                acc2.x = fmaf(b2, wv.x, acc2.x); acc2.y = fmaf(b2, wv.y, acc2.y);
                acc3.x = fmaf(b3, wv.x, acc3.x); acc3.y = fmaf(b3, wv.y, acc3.y);
            }
        }
        float* y = Y + (size_t)r0 * FD + lane * 2;
        *(float2*)&y[0]      = acc0;
        *(float2*)&y[FD]     = acc1;
        *(float2*)&y[2 * FD] = acc2;
        *(float2*)&y[3 * FD] = acc3;
    }
}

// ------------- per-node scalars: s[i]=h[i]@a[0:128], t[i]=h[i]@a[128:256] ---
__global__ __launch_bounds__(256) void k_nodedot(const float* __restrict__ H,
                                                 const float* __restrict__ aw,
                                                 float* __restrict__ S,
                                                 float* __restrict__ T) {
    const int row  = blockIdx.x * 4 + (threadIdx.x >> 6);
    const int lane = threadIdx.x & 63;
    float2 hv = *(const float2*)&H[(size_t)row * FD + lane * 2];
    float2 as = *(const float2*)&aw[lane * 2];
    float2 ad = *(const float2*)&aw[FD + lane * 2];
    float s = hv.x * as.x + hv.y * as.y;
    float t = hv.x * ad.x + hv.y * ad.y;
#pragma unroll
    for (int off = 32; off; off >>= 1) {
        s += __shfl_xor(s, off);
        t += __shfl_xor(t, off);
    }
    if (lane == 0) { S[row] = s; T[row] = t; }
}

// ---------------- per-edge weight: w = exp(leaky(s[src]+t[dst]+b)) ----------
__global__ void k_edge(const int* __restrict__ src, const int* __restrict__ dst,
                       const float* __restrict__ S, const float* __restrict__ T,
                       const float* __restrict__ b, float* __restrict__ w) {
    int e = blockIdx.x * 256 + threadIdx.x;
    if (e >= NE) return;
    float ev = S[src[e]] + T[dst[e]] + b[0];
    ev = (ev >= 0.f) ? ev : SLOPE * ev;
    w[e] = expf(ev);
}

// ---------------- CSR build: histogram, scan, scatter ----------------------
__global__ void k_hist(const int* __restrict__ src, int* __restrict__ counts) {
    int e = blockIdx.x * 256 + threadIdx.x;
    if (e < NE) atomicAdd(&counts[src[e]], 1);
}

__global__ __launch_bounds__(256) void k_scanA(const int* __restrict__ counts,
                                               int* __restrict__ incl,
                                               int* __restrict__ bsum) {
    __shared__ int lds[256];
    int i = blockIdx.x * 256 + threadIdx.x;
    lds[threadIdx.x] = (i < NN) ? counts[i] : 0;
    __syncthreads();
#pragma unroll
    for (int off = 1; off < 256; off <<= 1) {
        int add = (threadIdx.x >= off) ? lds[threadIdx.x - off] : 0;
        __syncthreads();
        lds[threadIdx.x] += add;
        __syncthreads();
    }
    if (i < NN) incl[i] = lds[threadIdx.x];
    if (threadIdx.x == 255) bsum[blockIdx.x] = lds[255];
}

__global__ __launch_bounds__(256) void k_scanB(const int* __restrict__ bsum,
                                               int* __restrict__ bscan, int nb) {
    __shared__ int lds[256];
    lds[threadIdx.x] = (threadIdx.x < nb) ? bsum[threadIdx.x] : 0;
    __syncthreads();
#pragma unroll
    for (int off = 1; off < 256; off <<= 1) {
        int add = (threadIdx.x >= off) ? lds[threadIdx.x - off] : 0;
        __syncthreads();
        lds[threadIdx.x] += add;
        __syncthreads();
    }
    bscan[threadIdx.x] = lds[threadIdx.x];
}

__global__ void k_scanC(const int* __restrict__ incl, const int* __restrict__ bscan,
                        int* __restrict__ rowptr) {
    int i = blockIdx.x * 256 + threadIdx.x;
    if (i < NN) {
        int off = (blockIdx.x > 0) ? bscan[blockIdx.x - 1] : 0;
        rowptr[i + 1] = incl[i] + off;
        if (i == 0) rowptr[0] = 0;
    }
}

__global__ void k_scatter(const int* __restrict__ src, const int* __restrict__ rowptr,
                          int* __restrict__ cursor, int* __restrict__ eid) {
    int e = blockIdx.x * 256 + threadIdx.x;
    if (e < NE) {
        int s = src[e];
        int pos = rowptr[s] + atomicAdd(&cursor[s], 1);
        eid[pos] = e;
    }
}

// ---------------- aggregation: OUT[r] = relu( (1/denom) * sum w_e * H[dst_e] )
// One wave per row; lane l owns feature dims {2l, 2l+1}.
__global__ __launch_bounds__(256) void k_agg(const int* __restrict__ rowptr,
                                             const int* __restrict__ eid,
                                             const int* __restrict__ dst,
                                             const float* __restrict__ w,
                                             const float* __restrict__ H,
                                             float* __restrict__ OUT,
                                             float* __restrict__ denom) {
    const int row  = blockIdx.x * 4 + (threadIdx.x >> 6);
    const int lane = threadIdx.x & 63;
    const int beg = rowptr[row], end = rowptr[row + 1];
    float2 acc = make_float2(0.f, 0.f);
    float dsum = 0.f;
    for (int j = beg; j < end; ++j) {
        int e = eid[j];
        float wv = w[e];
        int d = dst[e];
        float2 hv = *(const float2*)&H[(size_t)d * FD + lane * 2];
        acc.x = fmaf(wv, hv.x, acc.x);
        acc.y = fmaf(wv, hv.y, acc.y);
        dsum += wv;
    }
    float inv = (dsum > 0.f) ? (1.f / dsum) : 0.f;
    float2 o;
    o.x = fmaxf(acc.x * inv, 0.f);
    o.y = fmaxf(acc.y * inv, 0.f);
    *(float2*)&OUT[(size_t)row * FD + lane * 2] = o;
    if (lane == 0) denom[row] = dsum;
}

// ---------------- alpha2 output --------------------------------------------
__global__ void k_alpha(const float* __restrict__ w, const int* __restrict__ src,
                        const float* __restrict__ denom, float* __restrict__ oa) {
    int e = blockIdx.x * 256 + threadIdx.x;
    if (e < NE) oa[e] = w[e] / denom[src[e]];
}

// ---------------- fc (128->16) + row log-softmax ----------------------------
__global__ __launch_bounds__(256) void k_fc(const float* __restrict__ H,
                                            const float* __restrict__ fcW,
                                            const float* __restrict__ fcb,
                                            float* __restrict__ out) {
    __shared__ float Wl[FD * NC];
    __shared__ float bl[NC];
    for (int i = threadIdx.x; i < FD * NC; i += 256) Wl[i] = fcW[i];
    if (threadIdx.x < NC) bl[threadIdx.x] = fcb[threadIdx.x];
    __syncthreads();
    const int sub = threadIdx.x >> 4;   // 16 rows per block-iteration
    const int c   = threadIdx.x & 15;
    for (int row = blockIdx.x * 16 + sub; row < NN; row += gridDim.x * 16) {
        const float* __restrict__ h = H + (size_t)row * FD;
        float acc = bl[c];
#pragma unroll 8
        for (int k = 0; k < FD; k += 4) {
            float4 hv = *(const float4*)&h[k];
            acc = fmaf(hv.x, Wl[k * NC + c], acc);
            acc = fmaf(hv.y, Wl[(k + 1) * NC + c], acc);
            acc = fmaf(hv.z, Wl[(k + 2) * NC + c], acc);
            acc = fmaf(hv.w, Wl[(k + 3) * NC + c], acc);
        }
        float m = acc;
#pragma unroll
        for (int off = 1; off < NC; off <<= 1) m = fmaxf(m, __shfl_xor(m, off));
        float ex = expf(acc - m);
        float ssum = ex;
#pragma unroll
        for (int off = 1; off < NC; off <<= 1) ssum += __shfl_xor(ssum, off);
        out[(size_t)row * NC + c] = (acc - m) - logf(ssum);
    }
}

extern "C" void kernel_launch(void* const* d_in, const int* in_sizes, int n_in,
                              void* d_out, int out_size, void* d_ws, size_t ws_size,
                              hipStream_t stream) {
    const float* x   = (const float*)d_in[0];
    const int*   src = (const int*)d_in[1];
    const int*   dst = (const int*)d_in[2];
    const float* W1  = (const float*)d_in[3];
    const float* a1w = (const float*)d_in[4];
    const float* a1b = (const float*)d_in[5];
    const float* W2  = (const float*)d_in[6];
    const float* a2w = (const float*)d_in[7];
    const float* a2b = (const float*)d_in[8];
    const float* fcW = (const float*)d_in[9];
    const float* fcb = (const float*)d_in[10];

    float* out_lsm   = (float*)d_out;                         // 50000*16
    float* out_alpha = (float*)d_out + (size_t)NN * NC;       // 800000

    char* ws = (char*)d_ws;
    float* h_buf = (float*)ws; ws += (size_t)NN * FD * 4;     // 25.6 MB
    float* g_buf = (float*)ws; ws += (size_t)NN * FD * 4;     // 25.6 MB
    float* w_buf = (float*)ws; ws += (size_t)NE * 4;          // 3.2 MB
    int*   eid   = (int*)ws;   ws += (size_t)NE * 4;          // 3.2 MB
    float* sbuf  = (float*)ws; ws += (size_t)NN * 4;
    float* tbuf  = (float*)ws; ws += (size_t)NN * 4;
    float* denom = (float*)ws; ws += (size_t)NN * 4;
    int* counts  = (int*)ws;   ws += (size_t)NN * 4;
    int* cursor  = (int*)ws;   ws += (size_t)NN * 4;          // adjacent to counts
    int* rowptr  = (int*)ws;   ws += (size_t)(NN + 1) * 4;
    int* incl    = (int*)ws;   ws += (size_t)NN * 4;
    int* bsum    = (int*)ws;   ws += 256 * 4;
    int* bscan   = (int*)ws;   ws += 256 * 4;

    const dim3 b256(256);
    const int nbN = (NN + 255) / 256;   // 196
    const int nbE = (NE + 255) / 256;   // 3125

    // CSR build (graph is identical for both layers)
    hipMemsetAsync(counts, 0, (size_t)NN * 4 * 2, stream);    // counts + cursor
    k_hist   <<<dim3(nbE), b256, 0, stream>>>(src, counts);
    k_scanA  <<<dim3(nbN), b256, 0, stream>>>(counts, incl, bsum);
    k_scanB  <<<dim3(1),   b256, 0, stream>>>(bsum, bscan, nbN);
    k_scanC  <<<dim3(nbN), b256, 0, stream>>>(incl, bscan, rowptr);
    k_scatter<<<dim3(nbE), b256, 0, stream>>>(src, rowptr, cursor, eid);

    // Layer 1
    k_gemm128<<<dim3(1024), b256, 0, stream>>>(x, W1, h_buf);
    k_nodedot<<<dim3(NN / 4), b256, 0, stream>>>(h_buf, a1w, sbuf, tbuf);
    k_edge   <<<dim3(nbE), b256, 0, stream>>>(src, dst, sbuf, tbuf, a1b, w_buf);
    k_agg    <<<dim3(NN / 4), b256, 0, stream>>>(rowptr, eid, dst, w_buf, h_buf, g_buf, denom);

    // Layer 2
    k_gemm128<<<dim3(1024), b256, 0, stream>>>(g_buf, W2, h_buf);
    k_nodedot<<<dim3(NN / 4), b256, 0, stream>>>(h_buf, a2w, sbuf, tbuf);
    k_edge   <<<dim3(nbE), b256, 0, stream>>>(src, dst, sbuf, tbuf, a2b, w_buf);
    k_agg    <<<dim3(NN / 4), b256, 0, stream>>>(rowptr, eid, dst, w_buf, h_buf, g_buf, denom);

    // Outputs
    k_alpha<<<dim3(nbE), b256, 0, stream>>>(w_buf, src, denom, out_alpha);
    k_fc   <<<dim3(1024), b256, 0, stream>>>(g_buf, fcW, fcb, out_lsm);
}